// Round 1
// baseline (887.872 us; speedup 1.0000x reference)
//
#include <hip/hip_runtime.h>

#define NVERT 6890
#define NFACE 13776
#define SS 256
#define NPIX (SS*SS)

// ---- exact-rounding helpers (no FMA contraction on the decision path) ----
static __device__ __forceinline__ float edgef(float ax, float ay, float bx, float by,
                                              float px, float py) {
  // (ax-px)*(by-py) - (ay-py)*(bx-px), IEEE fp32, no fusion
  return __fsub_rn(__fmul_rn(__fsub_rn(ax, px), __fsub_rn(by, py)),
                   __fmul_rn(__fsub_rn(ay, py), __fsub_rn(bx, px)));
}

// vb layout: per vertex [sx, sy, cz]  (sx,sy = pts2d; cz = vz + 2.7320508)
__global__ __launch_bounds__(256) void vert_k(const float* __restrict__ cam,
                                              const float* __restrict__ verts,
                                              float* __restrict__ vb) {
  int i = blockIdx.x * 256 + threadIdx.x;
  if (i >= NVERT) return;
  float c0 = cam[0], c1 = cam[1], c2 = cam[2];
  float vx = verts[i*3+0], vy = verts[i*3+1], vz = verts[i*3+2];
  vb[i*3+0] = __fmul_rn(c0, __fadd_rn(vx, c1));
  vb[i*3+1] = __fmul_rn(c0, __fadd_rn(vy, c2));
  vb[i*3+2] = __fadd_rn(vz, 2.7320508075688776f);  // vz - eye_z
}

__global__ __launch_bounds__(256) void init_k(unsigned long long* __restrict__ keys) {
  int p = blockIdx.x * 256 + threadIdx.x;
  if (p < NPIX) keys[p] = 0xFFFFFFFFFFFFFFFFULL;
}

// texture sampling: one thread per (face, sample t in 0..8)
__global__ __launch_bounds__(256) void tex_k(const float* __restrict__ vb,
                                             const int* __restrict__ faces,
                                             const float* __restrict__ uv,
                                             float* __restrict__ texb,
                                             float* __restrict__ out_tex) {
  int tid = blockIdx.x * 256 + threadIdx.x;
  if (tid >= NFACE * 9) return;
  int f = tid / 9, t = tid - f * 9;
  int ti = t / 3, tj = t - ti * 3;
  float xt = 0.5f * (float)ti;   // ab = [0, 0.5, 1]
  float yt = 0.5f * (float)tj;
  int ia = faces[f*3+0], ib = faces[f*3+1], ic = faces[f*3+2];
  float ax = vb[ia*3+0], ay = vb[ia*3+1];
  float bx = vb[ib*3+0], by = vb[ib*3+1];
  float cx = vb[ic*3+0], cy = vb[ic*3+1];
  float sx = (ax - cx) * xt + (bx - cx) * yt + cx;
  float sy = (ay - cy) * xt + (by - cy) * yt + cy;
  sx = fminf(fmaxf(sx, -1.f), 1.f);
  sy = fminf(fmaxf(sy, -1.f), 1.f);
  float gx = (sx + 1.f) * 128.f - 0.5f;
  float gy = (sy + 1.f) * 128.f - 0.5f;
  float x0f = floorf(gx), y0f = floorf(gy);
  float fx = gx - x0f, fy = gy - y0f;
  int x0 = (int)x0f, y0 = (int)y0f;
  float r = 0.f, g = 0.f, b = 0.f;
  #pragma unroll
  for (int dy = 0; dy < 2; ++dy) {
    #pragma unroll
    for (int dx = 0; dx < 2; ++dx) {
      int xi = x0 + dx, yi = y0 + dy;
      if (xi >= 0 && xi < SS && yi >= 0 && yi < SS) {
        float w = (dx ? fx : 1.f - fx) * (dy ? fy : 1.f - fy);
        int base = yi * SS + xi;
        r += w * uv[base];
        g += w * uv[NPIX + base];
        b += w * uv[2 * NPIX + base];
      }
    }
  }
  int o = (f * 9 + t) * 3;
  texb[o+0] = r; texb[o+1] = g; texb[o+2] = b;
  // textures output: (1,NF,3,3,3,3), value independent of 3rd T index (repeat)
  float* ot = out_tex + f * 81 + ti * 27 + tj * 9;
  #pragma unroll
  for (int kk = 0; kk < 3; ++kk) {
    ot[kk*3+0] = r; ot[kk*3+1] = g; ot[kk*3+2] = b;
  }
}

// rasterize: one 64-lane wave per face, iterate bbox pixels
__global__ __launch_bounds__(256) void rast_k(const float* __restrict__ vb,
                                              const int* __restrict__ faces,
                                              unsigned long long* __restrict__ keys) {
  int wave = threadIdx.x >> 6;
  int lane = threadIdx.x & 63;
  int f = blockIdx.x * 4 + wave;
  if (f >= NFACE) return;
  int ia = faces[f*3+0], ib = faces[f*3+1], ic = faces[f*3+2];
  float x0 = vb[ia*3+0], y0 = -vb[ia*3+1], z0 = vb[ia*3+2];
  float x1 = vb[ib*3+0], y1 = -vb[ib*3+1], z1 = vb[ib*3+2];
  float x2 = vb[ic*3+0], y2 = -vb[ic*3+1], z2 = vb[ic*3+2];
  float det = edgef(x1, y1, x2, y2, x0, y0);
  if (!(det > 1e-10f)) return;                       // backface / degenerate cull
  float rz0 = (fabsf(z0) > 1e-8f) ? z0 : 1.0f;
  float rz1 = (fabsf(z1) > 1e-8f) ? z1 : 1.0f;
  float rz2 = (fabsf(z2) > 1e-8f) ? z2 : 1.0f;
  // pixel bbox: px = (2x+1-256)/256  =>  x = (px*256+255)/2 ; pad by 2 px
  float mnx = fminf(x0, fminf(x1, x2)), mxx = fmaxf(x0, fmaxf(x1, x2));
  float mny = fminf(y0, fminf(y1, y2)), mxy = fmaxf(y0, fmaxf(y1, y2));
  int xlo = (int)floorf((mnx * 256.f + 255.f) * 0.5f) - 2;
  int xhi = (int)ceilf ((mxx * 256.f + 255.f) * 0.5f) + 2;
  int ylo = (int)floorf((mny * 256.f + 255.f) * 0.5f) - 2;
  int yhi = (int)ceilf ((mxy * 256.f + 255.f) * 0.5f) + 2;
  xlo = max(xlo, 0); ylo = max(ylo, 0);
  xhi = min(xhi, SS - 1); yhi = min(yhi, SS - 1);
  if (xlo > xhi || ylo > yhi) return;
  int bw = xhi - xlo + 1;
  int tot = bw * (yhi - ylo + 1);
  for (int idx = lane; idx < tot; idx += 64) {
    int xx = xlo + idx % bw;
    int yy = ylo + idx / bw;
    float px = (float)(2 * xx + 1 - SS) * (1.0f / 256.0f);  // exact
    float py = (float)(2 * yy + 1 - SS) * (1.0f / 256.0f);
    float e0 = edgef(x1, y1, x2, y2, px, py);
    float e1 = edgef(x2, y2, x0, y0, px, py);
    float e2 = edgef(x0, y0, x1, y1, px, py);
    if (e0 >= 0.f && e1 >= 0.f && e2 >= 0.f) {
      float b0 = __fdiv_rn(e0, det);
      float b1 = __fdiv_rn(e1, det);
      float b2 = __fdiv_rn(e2, det);
      float inv = __fadd_rn(__fadd_rn(__fdiv_rn(b0, rz0), __fdiv_rn(b1, rz1)),
                            __fdiv_rn(b2, rz2));
      if (!(fabsf(inv) > 1e-8f)) inv = 1.0f;
      float zp = __fdiv_rn(1.0f, inv);
      if (zp > 0.1f && zp < 25.0f) {
        unsigned long long key =
            ((unsigned long long)__float_as_uint(zp) << 32) | (unsigned int)f;
        unsigned long long* kp = &keys[yy * SS + xx];
        if (key < *kp) atomicMin(kp, key);   // pre-read prune; race-benign (monotone)
      }
    }
  }
}

// resolve: one thread per pixel -> images output
__global__ __launch_bounds__(256) void resolve_k(const float* __restrict__ vb,
                                                 const int* __restrict__ faces,
                                                 const unsigned long long* __restrict__ keys,
                                                 const float* __restrict__ texb,
                                                 float* __restrict__ out_img) {
  int p = blockIdx.x * 256 + threadIdx.x;
  if (p >= NPIX) return;
  unsigned long long k = keys[p];
  float c0 = 0.f, c1 = 0.f, c2 = 0.f;
  if (k != 0xFFFFFFFFFFFFFFFFULL) {
    int f = (int)(unsigned int)(k & 0xFFFFFFFFULL);
    float bz = __uint_as_float((unsigned int)(k >> 32));
    int xx = p & (SS - 1), yy = p >> 8;
    float px = (float)(2 * xx + 1 - SS) * (1.0f / 256.0f);
    float py = (float)(2 * yy + 1 - SS) * (1.0f / 256.0f);
    int ia = faces[f*3+0], ib = faces[f*3+1], ic = faces[f*3+2];
    float x0 = vb[ia*3+0], y0 = -vb[ia*3+1], z0 = vb[ia*3+2];
    float x1 = vb[ib*3+0], y1 = -vb[ib*3+1], z1 = vb[ib*3+2];
    float x2 = vb[ic*3+0], y2 = -vb[ic*3+1], z2 = vb[ic*3+2];
    float det = edgef(x1, y1, x2, y2, x0, y0);    // winner => det > 1e-10
    float e0 = edgef(x1, y1, x2, y2, px, py);
    float e1 = edgef(x2, y2, x0, y0, px, py);
    float e2 = edgef(x0, y0, x1, y1, px, py);
    float b0 = __fdiv_rn(e0, det);
    float b1 = __fdiv_rn(e1, det);
    float b2 = __fdiv_rn(e2, det);
    float rz0 = (fabsf(z0) > 1e-8f) ? z0 : 1.0f;
    float rz1 = (fabsf(z1) > 1e-8f) ? z1 : 1.0f;
    float rz2 = (fabsf(z2) > 1e-8f) ? z2 : 1.0f;
    // perspective-corrected barycentrics: (b_i / z_i) * zp
    float w0 = __fmul_rn(__fdiv_rn(b0, rz0), bz);
    float w1 = __fmul_rn(__fdiv_rn(b1, rz1), bz);
    float w2 = __fmul_rn(__fdiv_rn(b2, rz2), bz);
    // trilinear over T=3 grid (3rd dim is a repeat => index collapses, weights kept)
    float pos0 = fminf(fmaxf(w0, 0.f), 1.f) * 2.f;
    float pos1 = fminf(fmaxf(w1, 0.f), 1.f) * 2.f;
    float pos2 = fminf(fmaxf(w2, 0.f), 1.f) * 2.f;
    float i0f = fminf(fmaxf(floorf(pos0), 0.f), 1.f);
    float i1f = fminf(fmaxf(floorf(pos1), 0.f), 1.f);
    float i2f = fminf(fmaxf(floorf(pos2), 0.f), 1.f);
    float fr0 = fminf(fmaxf(__fsub_rn(pos0, i0f), 0.f), 1.f);
    float fr1 = fminf(fmaxf(__fsub_rn(pos1, i1f), 0.f), 1.f);
    float fr2 = fminf(fmaxf(__fsub_rn(pos2, i2f), 0.f), 1.f);
    int i00 = (int)i0f, i01 = (int)i1f;
    #pragma unroll
    for (int d0 = 0; d0 < 2; ++d0) {
      float wa = d0 ? fr0 : __fsub_rn(1.f, fr0);
      #pragma unroll
      for (int d1 = 0; d1 < 2; ++d1) {
        float wb = d1 ? fr1 : __fsub_rn(1.f, fr1);
        int a = min(i00 + d0, 2);
        int b = min(i01 + d1, 2);
        const float* tp = &texb[(f * 9 + a * 3 + b) * 3];
        float wab = __fmul_rn(wa, wb);
        #pragma unroll
        for (int d2 = 0; d2 < 2; ++d2) {
          float wc = d2 ? fr2 : __fsub_rn(1.f, fr2);
          float wgt = __fmul_rn(wab, wc);
          c0 = __fadd_rn(c0, __fmul_rn(wgt, tp[0]));
          c1 = __fadd_rn(c1, __fmul_rn(wgt, tp[1]));
          c2 = __fadd_rn(c2, __fmul_rn(wgt, tp[2]));
        }
      }
    }
  }
  out_img[p]           = c0;
  out_img[NPIX + p]    = c1;
  out_img[2*NPIX + p]  = c2;
}

extern "C" void kernel_launch(void* const* d_in, const int* in_sizes, int n_in,
                              void* d_out, int out_size, void* d_ws, size_t ws_size,
                              hipStream_t stream) {
  const float* cam   = (const float*)d_in[0];
  const float* verts = (const float*)d_in[1];
  const float* uv    = (const float*)d_in[2];
  const int*   faces = (const int*)d_in[3];
  float* out_img = (float*)d_out;            // (1,3,256,256) = 196608 floats
  float* out_tex = (float*)d_out + 3 * NPIX; // (1,NF,3,3,3,3) = 1115856 floats

  char* ws = (char*)d_ws;
  unsigned long long* keys = (unsigned long long*)ws;             // 512 KiB
  float* vb   = (float*)(ws + (size_t)NPIX * 8);                  // NVERT*3*4 B
  float* texb = (float*)(ws + (size_t)NPIX * 8 + ((NVERT*3*4 + 255)/256)*256); // NF*27*4 B

  vert_k<<<(NVERT + 255) / 256, 256, 0, stream>>>(cam, verts, vb);
  init_k<<<NPIX / 256, 256, 0, stream>>>(keys);
  tex_k<<<(NFACE * 9 + 255) / 256, 256, 0, stream>>>(vb, faces, uv, texb, out_tex);
  rast_k<<<(NFACE + 3) / 4, 256, 0, stream>>>(vb, faces, keys);
  resolve_k<<<NPIX / 256, 256, 0, stream>>>(vb, faces, keys, texb, out_img);
}

// Round 4
// 713.023 us; speedup vs baseline: 1.2452x; 1.2452x over previous
//
#include <hip/hip_runtime.h>

#define NVERT 6890
#define NFACE 13776
#define SS 256
#define NPIX (SS*SS)
#define NBLK_RAST 2048
#define NWAVES (NBLK_RAST*4)

// ws layout (byte offsets) — total < 1.33 MB (round 1 proved >= 2.09 MB works)
#define OFF_KEYS 0u
#define OFF_VB   524288u                 // keys: NPIX*8
#define OFF_FD   607232u                 // vb: NVERT*3*4 padded
#define OFF_PFX  1268480u                // fd: NFACE*12*4
// pfx: (NFACE+1)*4 = 55,108 -> ends at 1,323,588

// ---- exact-rounding helpers (no FMA contraction on the decision path) ----
static __device__ __forceinline__ float edgef(float ax, float ay, float bx, float by,
                                              float px, float py) {
  return __fsub_rn(__fmul_rn(__fsub_rn(ax, px), __fsub_rn(by, py)),
                   __fmul_rn(__fsub_rn(ay, py), __fsub_rn(bx, px)));
}

// vb layout: per vertex [sx, sy, cz]
__global__ __launch_bounds__(256) void vert_k(const float* __restrict__ cam,
                                              const float* __restrict__ verts,
                                              float* __restrict__ vb) {
  int i = blockIdx.x * 256 + threadIdx.x;
  if (i >= NVERT) return;
  float c0 = cam[0], c1 = cam[1], c2 = cam[2];
  float vx = verts[i*3+0], vy = verts[i*3+1], vz = verts[i*3+2];
  vb[i*3+0] = __fmul_rn(c0, __fadd_rn(vx, c1));
  vb[i*3+1] = __fmul_rn(c0, __fadd_rn(vy, c2));
  vb[i*3+2] = __fadd_rn(vz, 2.7320508075688776f);
}

__global__ __launch_bounds__(256) void init_k(unsigned long long* __restrict__ keys) {
  int p = blockIdx.x * 256 + threadIdx.x;
  if (p < NPIX) keys[p] = 0xFFFFFFFFFFFFFFFFULL;
}

// texture sampling: one thread per (face, sample t in 0..8); writes out_tex only
__global__ __launch_bounds__(256) void tex_k(const float* __restrict__ vb,
                                             const int* __restrict__ faces,
                                             const float* __restrict__ uv,
                                             float* __restrict__ out_tex) {
  int tid = blockIdx.x * 256 + threadIdx.x;
  if (tid >= NFACE * 9) return;
  int f = tid / 9, t = tid - f * 9;
  int ti = t / 3, tj = t - ti * 3;
  float xt = 0.5f * (float)ti;
  float yt = 0.5f * (float)tj;
  int ia = faces[f*3+0], ib = faces[f*3+1], ic = faces[f*3+2];
  float ax = vb[ia*3+0], ay = vb[ia*3+1];
  float bx = vb[ib*3+0], by = vb[ib*3+1];
  float cx = vb[ic*3+0], cy = vb[ic*3+1];
  float sx = (ax - cx) * xt + (bx - cx) * yt + cx;
  float sy = (ay - cy) * xt + (by - cy) * yt + cy;
  sx = fminf(fmaxf(sx, -1.f), 1.f);
  sy = fminf(fmaxf(sy, -1.f), 1.f);
  float gx = (sx + 1.f) * 128.f - 0.5f;
  float gy = (sy + 1.f) * 128.f - 0.5f;
  float x0f = floorf(gx), y0f = floorf(gy);
  float fx = gx - x0f, fy = gy - y0f;
  int x0 = (int)x0f, y0 = (int)y0f;
  float r = 0.f, g = 0.f, b = 0.f;
  #pragma unroll
  for (int dy = 0; dy < 2; ++dy) {
    #pragma unroll
    for (int dx = 0; dx < 2; ++dx) {
      int xi = x0 + dx, yi = y0 + dy;
      if (xi >= 0 && xi < SS && yi >= 0 && yi < SS) {
        float w = (dx ? fx : 1.f - fx) * (dy ? fy : 1.f - fy);
        int base = yi * SS + xi;
        r += w * uv[base];
        g += w * uv[NPIX + base];
        b += w * uv[2 * NPIX + base];
      }
    }
  }
  // textures output: (1,NF,3,3,3,3); value independent of 3rd T index (repeat)
  float* ot = out_tex + f * 81 + ti * 27 + tj * 9;
  #pragma unroll
  for (int kk = 0; kk < 3; ++kk) {
    ot[kk*3+0] = r; ot[kk*3+1] = g; ot[kk*3+2] = b;
  }
}

// per-face setup: cull, bbox, 12-float record + chunk count into pfx[f]
__global__ __launch_bounds__(256) void setup_k(const float* __restrict__ vb,
                                               const int* __restrict__ faces,
                                               float* __restrict__ fd,
                                               unsigned int* __restrict__ pfx) {
  int f = blockIdx.x * 256 + threadIdx.x;
  if (f >= NFACE) return;
  unsigned int nch = 0;
  int ia = faces[f*3+0], ib = faces[f*3+1], ic = faces[f*3+2];
  float x0 = vb[ia*3+0], y0 = -vb[ia*3+1], z0 = vb[ia*3+2];
  float x1 = vb[ib*3+0], y1 = -vb[ib*3+1], z1 = vb[ib*3+2];
  float x2 = vb[ic*3+0], y2 = -vb[ic*3+1], z2 = vb[ic*3+2];
  float det = edgef(x1, y1, x2, y2, x0, y0);
  if (det > 1e-10f) {
    float mnx = fminf(x0, fminf(x1, x2)), mxx = fmaxf(x0, fmaxf(x1, x2));
    float mny = fminf(y0, fminf(y1, y2)), mxy = fmaxf(y0, fmaxf(y1, y2));
    int xlo = max((int)floorf((mnx * 256.f + 255.f) * 0.5f) - 2, 0);
    int xhi = min((int)ceilf ((mxx * 256.f + 255.f) * 0.5f) + 2, SS - 1);
    int ylo = max((int)floorf((mny * 256.f + 255.f) * 0.5f) - 2, 0);
    int yhi = min((int)ceilf ((mxy * 256.f + 255.f) * 0.5f) + 2, SS - 1);
    if (xlo <= xhi && ylo <= yhi) {
      int bw = xhi - xlo + 1;
      int cnt = bw * (yhi - ylo + 1);
      float* fp = fd + f * 12;
      fp[0] = x0; fp[1] = y0; fp[2] = x1; fp[3] = y1; fp[4] = x2; fp[5] = y2;
      fp[6] = (fabsf(z0) > 1e-8f) ? z0 : 1.0f;
      fp[7] = (fabsf(z1) > 1e-8f) ? z1 : 1.0f;
      fp[8] = (fabsf(z2) > 1e-8f) ? z2 : 1.0f;
      fp[9] = det;
      fp[10] = __uint_as_float((unsigned int)xlo | ((unsigned int)ylo << 8)
                               | ((unsigned int)bw << 16));
      fp[11] = __int_as_float(cnt);
      nch = (unsigned int)((cnt + 63) >> 6);
    }
  }
  pfx[f] = nch;
}

// single-block exclusive scan over pfx[0..NFACE); pfx[NFACE] = total
__global__ __launch_bounds__(1024) void scan_k(unsigned int* __restrict__ pfx) {
  __shared__ unsigned int buf[1024];
  __shared__ unsigned int carry_s;
  int tid = threadIdx.x;
  if (tid == 0) carry_s = 0;
  __syncthreads();
  for (int base = 0; base < NFACE; base += 1024) {
    int i = base + tid;
    unsigned int v = (i < NFACE) ? pfx[i] : 0u;
    buf[tid] = v;
    __syncthreads();
    for (int off = 1; off < 1024; off <<= 1) {
      unsigned int t = (tid >= off) ? buf[tid - off] : 0u;
      __syncthreads();
      buf[tid] += t;
      __syncthreads();
    }
    unsigned int carry = carry_s;
    if (i < NFACE) pfx[i] = carry + buf[tid] - v;   // exclusive
    unsigned int tile_tot = buf[1023];
    __syncthreads();
    if (tid == 0) carry_s = carry + tile_tot;
    __syncthreads();
  }
  if (tid == 0) pfx[NFACE] = carry_s;
}

// balanced rasterizer: contiguous chunk ranges per wave; 1 chunk = 64 px
__global__ __launch_bounds__(256) void rast2_k(const float* __restrict__ fd,
                                               const unsigned int* __restrict__ pfx,
                                               unsigned long long* __restrict__ keys) {
  unsigned int total = pfx[NFACE];
  if (total == 0) return;
  int lane = threadIdx.x & 63;
  unsigned int gw = blockIdx.x * 4u + (unsigned int)(threadIdx.x >> 6);
  unsigned int per = (total + NWAVES - 1) / NWAVES;
  unsigned int start = gw * per;
  unsigned int end = min(start + per, total);
  if (start >= end) return;
  // uniform binary search: largest f with pfx[f] <= start
  unsigned int lo = 0, hi = NFACE - 1;
  while (lo < hi) {
    unsigned int mid = (lo + hi + 1) >> 1;
    if (pfx[mid] <= start) lo = mid; else hi = mid - 1;
  }
  unsigned int f = lo;
  unsigned int fstart = pfx[f];
  unsigned int fend = pfx[f + 1];
  for (unsigned int c = start; c < end; ++c) {
    while (c >= fend) { ++f; fstart = fend; fend = pfx[f + 1]; }
    const float* fp = fd + f * 12;
    float x0 = fp[0], y0 = fp[1], x1 = fp[2], y1 = fp[3], x2 = fp[4], y2 = fp[5];
    float rz0 = fp[6], rz1 = fp[7], rz2 = fp[8], det = fp[9];
    unsigned int pack = __float_as_uint(fp[10]);
    int cnt = __float_as_int(fp[11]);
    int xlo = (int)(pack & 255u), ylo = (int)((pack >> 8) & 255u);
    int bw  = (int)(pack >> 16);
    int idx = (int)((c - fstart) << 6) + lane;
    if (idx < cnt) {
      int q = idx / bw;
      int xx = xlo + (idx - q * bw);
      int yy = ylo + q;
      float px = (float)(2 * xx + 1 - SS) * (1.0f / 256.0f);
      float py = (float)(2 * yy + 1 - SS) * (1.0f / 256.0f);
      float e0 = edgef(x1, y1, x2, y2, px, py);
      float e1 = edgef(x2, y2, x0, y0, px, py);
      float e2 = edgef(x0, y0, x1, y1, px, py);
      if (e0 >= 0.f && e1 >= 0.f && e2 >= 0.f) {
        float b0 = __fdiv_rn(e0, det);
        float b1 = __fdiv_rn(e1, det);
        float b2 = __fdiv_rn(e2, det);
        float inv = __fadd_rn(__fadd_rn(__fdiv_rn(b0, rz0), __fdiv_rn(b1, rz1)),
                              __fdiv_rn(b2, rz2));
        if (!(fabsf(inv) > 1e-8f)) inv = 1.0f;
        float zp = __fdiv_rn(1.0f, inv);
        if (zp > 0.1f && zp < 25.0f) {
          unsigned long long key =
              ((unsigned long long)__float_as_uint(zp) << 32) | f;
          unsigned long long* kp = &keys[yy * SS + xx];
          if (key < *kp) atomicMin(kp, key);   // staleness-safe prune
        }
      }
    }
  }
}

// resolve: one thread per pixel -> images output (exact reference chain)
__global__ __launch_bounds__(256) void resolve_k(const float* __restrict__ vb,
                                                 const int* __restrict__ faces,
                                                 const unsigned long long* __restrict__ keys,
                                                 const float* __restrict__ out_tex,
                                                 float* __restrict__ out_img) {
  int p = blockIdx.x * 256 + threadIdx.x;
  if (p >= NPIX) return;
  unsigned long long k = keys[p];
  float c0 = 0.f, c1 = 0.f, c2 = 0.f;
  if (k != 0xFFFFFFFFFFFFFFFFULL) {
    int f = (int)(unsigned int)(k & 0xFFFFFFFFULL);
    float bz = __uint_as_float((unsigned int)(k >> 32));
    int xx = p & (SS - 1), yy = p >> 8;
    float px = (float)(2 * xx + 1 - SS) * (1.0f / 256.0f);
    float py = (float)(2 * yy + 1 - SS) * (1.0f / 256.0f);
    int ia = faces[f*3+0], ib = faces[f*3+1], ic = faces[f*3+2];
    float x0 = vb[ia*3+0], y0 = -vb[ia*3+1], z0 = vb[ia*3+2];
    float x1 = vb[ib*3+0], y1 = -vb[ib*3+1], z1 = vb[ib*3+2];
    float x2 = vb[ic*3+0], y2 = -vb[ic*3+1], z2 = vb[ic*3+2];
    float det = edgef(x1, y1, x2, y2, x0, y0);
    float e0 = edgef(x1, y1, x2, y2, px, py);
    float e1 = edgef(x2, y2, x0, y0, px, py);
    float e2 = edgef(x0, y0, x1, y1, px, py);
    float b0 = __fdiv_rn(e0, det);
    float b1 = __fdiv_rn(e1, det);
    float b2 = __fdiv_rn(e2, det);
    float rz0 = (fabsf(z0) > 1e-8f) ? z0 : 1.0f;
    float rz1 = (fabsf(z1) > 1e-8f) ? z1 : 1.0f;
    float rz2 = (fabsf(z2) > 1e-8f) ? z2 : 1.0f;
    float w0 = __fmul_rn(__fdiv_rn(b0, rz0), bz);
    float w1 = __fmul_rn(__fdiv_rn(b1, rz1), bz);
    float w2 = __fmul_rn(__fdiv_rn(b2, rz2), bz);
    float pos0 = fminf(fmaxf(w0, 0.f), 1.f) * 2.f;
    float pos1 = fminf(fmaxf(w1, 0.f), 1.f) * 2.f;
    float pos2 = fminf(fmaxf(w2, 0.f), 1.f) * 2.f;
    float i0f = fminf(fmaxf(floorf(pos0), 0.f), 1.f);
    float i1f = fminf(fmaxf(floorf(pos1), 0.f), 1.f);
    float i2f = fminf(fmaxf(floorf(pos2), 0.f), 1.f);
    float fr0 = fminf(fmaxf(__fsub_rn(pos0, i0f), 0.f), 1.f);
    float fr1 = fminf(fmaxf(__fsub_rn(pos1, i1f), 0.f), 1.f);
    float fr2 = fminf(fmaxf(__fsub_rn(pos2, i2f), 0.f), 1.f);
    int i00 = (int)i0f, i01 = (int)i1f;
    #pragma unroll
    for (int d0 = 0; d0 < 2; ++d0) {
      float wa = d0 ? fr0 : __fsub_rn(1.f, fr0);
      #pragma unroll
      for (int d1 = 0; d1 < 2; ++d1) {
        float wb = d1 ? fr1 : __fsub_rn(1.f, fr1);
        int a = min(i00 + d0, 2);
        int b = min(i01 + d1, 2);
        const float* tp = &out_tex[f * 81 + a * 27 + b * 9];  // k=0 slice
        float wab = __fmul_rn(wa, wb);
        #pragma unroll
        for (int d2 = 0; d2 < 2; ++d2) {
          float wc = d2 ? fr2 : __fsub_rn(1.f, fr2);
          float wgt = __fmul_rn(wab, wc);
          c0 = __fadd_rn(c0, __fmul_rn(wgt, tp[0]));
          c1 = __fadd_rn(c1, __fmul_rn(wgt, tp[1]));
          c2 = __fadd_rn(c2, __fmul_rn(wgt, tp[2]));
        }
      }
    }
  }
  out_img[p]           = c0;
  out_img[NPIX + p]    = c1;
  out_img[2*NPIX + p]  = c2;
}

extern "C" void kernel_launch(void* const* d_in, const int* in_sizes, int n_in,
                              void* d_out, int out_size, void* d_ws, size_t ws_size,
                              hipStream_t stream) {
  const float* cam   = (const float*)d_in[0];
  const float* verts = (const float*)d_in[1];
  const float* uv    = (const float*)d_in[2];
  const int*   faces = (const int*)d_in[3];
  float* out_img = (float*)d_out;            // (1,3,256,256)
  float* out_tex = (float*)d_out + 3 * NPIX; // (1,NF,3,3,3,3)

  char* ws = (char*)d_ws;
  unsigned long long* keys = (unsigned long long*)(ws + OFF_KEYS);
  float* vb                = (float*)(ws + OFF_VB);
  float* fd                = (float*)(ws + OFF_FD);
  unsigned int* pfx        = (unsigned int*)(ws + OFF_PFX);

  vert_k<<<(NVERT + 255) / 256, 256, 0, stream>>>(cam, verts, vb);
  init_k<<<NPIX / 256, 256, 0, stream>>>(keys);
  tex_k<<<(NFACE * 9 + 255) / 256, 256, 0, stream>>>(vb, faces, uv, out_tex);
  setup_k<<<(NFACE + 255) / 256, 256, 0, stream>>>(vb, faces, fd, pfx);
  scan_k<<<1, 1024, 0, stream>>>(pfx);
  rast2_k<<<NBLK_RAST, 256, 0, stream>>>(fd, pfx, keys);
  resolve_k<<<NPIX / 256, 256, 0, stream>>>(vb, faces, keys, out_tex, out_img);
}

// Round 6
// 393.662 us; speedup vs baseline: 2.2554x; 1.8113x over previous
//
#include <hip/hip_runtime.h>

#define NVERT 6890
#define NFACE 13776
#define SS 256
#define NPIX (SS*SS)
#define NBLK_RAST 2048
#define NWAVES (NBLK_RAST*4)
#define SENTINEL 0x7F800000FFFFFFFFULL   // zp=+inf, face=0xFFFFFFFF

// ws layout (byte offsets) — total ~1.55 MB (< 2.09 MB proven in round 1)
#define OFF_KEYS 0u
#define OFF_VB   524288u                 // keys: NPIX*8
#define OFF_FD   607232u                 // vb: NVERT*3*4 padded
#define OFF_PFX  1488896u                // fd: NFACE*16*4 = 881,664
// pfx: (NFACE+1)*4 = 55,108 -> ends at 1,544,004

// ---- exact-rounding helpers (no FMA contraction on the decision path) ----
static __device__ __forceinline__ float edgef(float ax, float ay, float bx, float by,
                                              float px, float py) {
  return __fsub_rn(__fmul_rn(__fsub_rn(ax, px), __fsub_rn(by, py)),
                   __fmul_rn(__fsub_rn(ay, py), __fsub_rn(bx, px)));
}

// vb layout: per vertex [sx, sy, cz]
__global__ __launch_bounds__(256) void vert_k(const float* __restrict__ cam,
                                              const float* __restrict__ verts,
                                              float* __restrict__ vb) {
  int i = blockIdx.x * 256 + threadIdx.x;
  if (i >= NVERT) return;
  float c0 = cam[0], c1 = cam[1], c2 = cam[2];
  float vx = verts[i*3+0], vy = verts[i*3+1], vz = verts[i*3+2];
  vb[i*3+0] = __fmul_rn(c0, __fadd_rn(vx, c1));
  vb[i*3+1] = __fmul_rn(c0, __fadd_rn(vy, c2));
  vb[i*3+2] = __fadd_rn(vz, 2.7320508075688776f);
}

__global__ __launch_bounds__(256) void init_k(unsigned long long* __restrict__ keys) {
  int p = blockIdx.x * 256 + threadIdx.x;
  if (p < NPIX) keys[p] = SENTINEL;
}

// texture sampling: one thread per (face, sample t in 0..8); writes out_tex only
__global__ __launch_bounds__(256) void tex_k(const float* __restrict__ vb,
                                             const int* __restrict__ faces,
                                             const float* __restrict__ uv,
                                             float* __restrict__ out_tex) {
  int tid = blockIdx.x * 256 + threadIdx.x;
  if (tid >= NFACE * 9) return;
  int f = tid / 9, t = tid - f * 9;
  int ti = t / 3, tj = t - ti * 3;
  float xt = 0.5f * (float)ti;
  float yt = 0.5f * (float)tj;
  int ia = faces[f*3+0], ib = faces[f*3+1], ic = faces[f*3+2];
  float ax = vb[ia*3+0], ay = vb[ia*3+1];
  float bx = vb[ib*3+0], by = vb[ib*3+1];
  float cx = vb[ic*3+0], cy = vb[ic*3+1];
  float sx = (ax - cx) * xt + (bx - cx) * yt + cx;
  float sy = (ay - cy) * xt + (by - cy) * yt + cy;
  sx = fminf(fmaxf(sx, -1.f), 1.f);
  sy = fminf(fmaxf(sy, -1.f), 1.f);
  float gx = (sx + 1.f) * 128.f - 0.5f;
  float gy = (sy + 1.f) * 128.f - 0.5f;
  float x0f = floorf(gx), y0f = floorf(gy);
  float fx = gx - x0f, fy = gy - y0f;
  int x0 = (int)x0f, y0 = (int)y0f;
  float r = 0.f, g = 0.f, b = 0.f;
  #pragma unroll
  for (int dy = 0; dy < 2; ++dy) {
    #pragma unroll
    for (int dx = 0; dx < 2; ++dx) {
      int xi = x0 + dx, yi = y0 + dy;
      if (xi >= 0 && xi < SS && yi >= 0 && yi < SS) {
        float w = (dx ? fx : 1.f - fx) * (dy ? fy : 1.f - fy);
        int base = yi * SS + xi;
        r += w * uv[base];
        g += w * uv[NPIX + base];
        b += w * uv[2 * NPIX + base];
      }
    }
  }
  float* ot = out_tex + f * 81 + ti * 27 + tj * 9;
  #pragma unroll
  for (int kk = 0; kk < 3; ++kk) {
    ot[kk*3+0] = r; ot[kk*3+1] = g; ot[kk*3+2] = b;
  }
}

// per-face setup: cull, bbox, 16-float record + row-chunk count into pfx[f]
__global__ __launch_bounds__(256) void setup_k(const float* __restrict__ vb,
                                               const int* __restrict__ faces,
                                               float* __restrict__ fd,
                                               unsigned int* __restrict__ pfx) {
  int f = blockIdx.x * 256 + threadIdx.x;
  if (f >= NFACE) return;
  unsigned int nch = 0;
  int ia = faces[f*3+0], ib = faces[f*3+1], ic = faces[f*3+2];
  float x0 = vb[ia*3+0], y0 = -vb[ia*3+1], z0 = vb[ia*3+2];
  float x1 = vb[ib*3+0], y1 = -vb[ib*3+1], z1 = vb[ib*3+2];
  float x2 = vb[ic*3+0], y2 = -vb[ic*3+1], z2 = vb[ic*3+2];
  float det = edgef(x1, y1, x2, y2, x0, y0);
  if (det > 1e-10f) {
    float mnx = fminf(x0, fminf(x1, x2)), mxx = fmaxf(x0, fmaxf(x1, x2));
    float mny = fminf(y0, fminf(y1, y2)), mxy = fmaxf(y0, fmaxf(y1, y2));
    int xlo = max((int)floorf((mnx * 256.f + 255.f) * 0.5f) - 2, 0);
    int xhi = min((int)ceilf ((mxx * 256.f + 255.f) * 0.5f) + 2, SS - 1);
    int ylo = max((int)floorf((mny * 256.f + 255.f) * 0.5f) - 2, 0);
    int yhi = min((int)ceilf ((mxy * 256.f + 255.f) * 0.5f) + 2, SS - 1);
    if (xlo <= xhi && ylo <= yhi) {
      int w = xhi - xlo + 1, h = yhi - ylo + 1;
      unsigned int segs = (unsigned int)((w + 63) >> 6);       // 1..4
      unsigned int M = 65536u / segs + 1u;                     // exact magic for q<2^16
      float rz0 = (fabsf(z0) > 1e-8f) ? z0 : 1.0f;
      float rz1 = (fabsf(z1) > 1e-8f) ? z1 : 1.0f;
      float rz2 = (fabsf(z2) > 1e-8f) ? z2 : 1.0f;
      float minrz = fminf(fminf(fabsf(rz0), fabsf(rz1)), fabsf(rz2));
      unsigned int flag = (minrz < 0.05f) ? 1u : 0u;           // approx untrustworthy
      float* fp = fd + f * 16;
      fp[0] = x0; fp[1] = y0; fp[2] = x1; fp[3] = y1; fp[4] = x2; fp[5] = y2;
      fp[6] = rz0; fp[7] = rz1; fp[8] = rz2;
      fp[9] = det;
      fp[10] = __fdiv_rn(1.0f, det * rz0);                     // approx coeffs
      fp[11] = __fdiv_rn(1.0f, det * rz1);
      fp[12] = __fdiv_rn(1.0f, det * rz2);
      fp[13] = __uint_as_float((unsigned int)xlo | ((unsigned int)ylo << 8)
                               | ((unsigned int)xhi << 16) | (flag << 24));
      fp[14] = __uint_as_float(segs);
      fp[15] = __uint_as_float(M);
      nch = (unsigned int)h * segs;
    }
  }
  pfx[f] = nch;
}

// single-block exclusive scan over pfx[0..NFACE); pfx[NFACE] = total
__global__ __launch_bounds__(1024) void scan_k(unsigned int* __restrict__ pfx) {
  __shared__ unsigned int buf[1024];
  __shared__ unsigned int carry_s;
  int tid = threadIdx.x;
  if (tid == 0) carry_s = 0;
  __syncthreads();
  for (int base = 0; base < NFACE; base += 1024) {
    int i = base + tid;
    unsigned int v = (i < NFACE) ? pfx[i] : 0u;
    buf[tid] = v;
    __syncthreads();
    for (int off = 1; off < 1024; off <<= 1) {
      unsigned int t = (tid >= off) ? buf[tid - off] : 0u;
      __syncthreads();
      buf[tid] += t;
      __syncthreads();
    }
    unsigned int carry = carry_s;
    if (i < NFACE) pfx[i] = carry + buf[tid] - v;   // exclusive
    unsigned int tile_tot = buf[1023];
    __syncthreads();
    if (tid == 0) carry_s = carry + tile_tot;
    __syncthreads();
  }
  if (tid == 0) pfx[NFACE] = carry_s;
}

// balanced rasterizer: row-aligned 64-px chunks + conservative z-prefilter
__global__ __launch_bounds__(256) void rast2_k(const float* __restrict__ fd,
                                               const unsigned int* __restrict__ pfx,
                                               unsigned long long* __restrict__ keys) {
  unsigned int total = pfx[NFACE];
  if (total == 0) return;
  int lane = threadIdx.x & 63;
  unsigned int gw = (unsigned int)__builtin_amdgcn_readfirstlane(
      (int)(blockIdx.x * 4u + (unsigned int)(threadIdx.x >> 6)));
  unsigned int per = (total + NWAVES - 1) / NWAVES;
  unsigned int start = gw * per;
  unsigned int end = min(start + per, total);
  if (start >= end) return;
  // uniform binary search: largest f with pfx[f] <= start
  unsigned int lo = 0, hi = NFACE - 1;
  while (lo < hi) {
    unsigned int mid = (lo + hi + 1) >> 1;
    if (pfx[mid] <= start) lo = mid; else hi = mid - 1;
  }
  unsigned int f = (unsigned int)__builtin_amdgcn_readfirstlane((int)lo);
  unsigned int fstart = (unsigned int)__builtin_amdgcn_readfirstlane((int)pfx[f]);
  unsigned int fend   = (unsigned int)__builtin_amdgcn_readfirstlane((int)pfx[f + 1]);
  for (unsigned int c = start; c < end; ++c) {
    while (c >= fend) {
      ++f; fstart = fend;
      fend = (unsigned int)__builtin_amdgcn_readfirstlane((int)pfx[f + 1]);
    }
    const float* fp = fd + (size_t)f * 16;
    float x0 = fp[0], y0 = fp[1], x1 = fp[2], y1 = fp[3], x2 = fp[4], y2 = fp[5];
    unsigned int pk   = __float_as_uint(fp[13]);
    unsigned int segs = __float_as_uint(fp[14]);
    unsigned int M    = __float_as_uint(fp[15]);
    unsigned int q = c - fstart;
    unsigned int r = (q * M) >> 16;          // exact q/segs (q<2^16, segs<=4)
    unsigned int s2 = q - r * segs;
    int xx = (int)(pk & 255u) + (int)(s2 << 6) + lane;
    int yy = (int)((pk >> 8) & 255u) + (int)r;
    int xhi = (int)((pk >> 16) & 255u);
    if (xx <= xhi) {
      float px = (float)(2 * xx + 1 - SS) * (1.0f / 256.0f);
      float py = (float)(2 * yy + 1 - SS) * (1.0f / 256.0f);
      float e0 = edgef(x1, y1, x2, y2, px, py);
      float e1 = edgef(x2, y2, x0, y0, px, py);
      float e2 = edgef(x0, y0, x1, y1, px, py);
      if (e0 >= 0.f && e1 >= 0.f && e2 >= 0.f) {
        int pix = yy * SS + xx;
        unsigned long long cur = keys[pix];            // stale-safe (monotone)
        float zc = __uint_as_float((unsigned int)(cur >> 32));  // +inf at init
        float inva = __fmaf_rn(e0, fp[10], __fmaf_rn(e1, fp[11], e2 * fp[12]));
        bool pass = ((pk >> 24) != 0u) | (inva * zc > 0.998f) | (fabsf(inva) < 1e-4f);
        if (pass) {
          // exact reference chain (bit-identical decision path)
          float rz0 = fp[6], rz1 = fp[7], rz2 = fp[8], det = fp[9];
          float b0 = __fdiv_rn(e0, det);
          float b1 = __fdiv_rn(e1, det);
          float b2 = __fdiv_rn(e2, det);
          float inv = __fadd_rn(__fadd_rn(__fdiv_rn(b0, rz0), __fdiv_rn(b1, rz1)),
                                __fdiv_rn(b2, rz2));
          if (!(fabsf(inv) > 1e-8f)) inv = 1.0f;
          float zp = __fdiv_rn(1.0f, inv);
          if (zp > 0.1f && zp < 25.0f) {
            unsigned long long key =
                ((unsigned long long)__float_as_uint(zp) << 32) | f;
            if (key < cur) atomicMin(&keys[pix], key);
          }
        }
      }
    }
  }
}

// resolve: one thread per pixel -> images output (exact reference chain)
__global__ __launch_bounds__(256) void resolve_k(const float* __restrict__ vb,
                                                 const int* __restrict__ faces,
                                                 const unsigned long long* __restrict__ keys,
                                                 const float* __restrict__ out_tex,
                                                 float* __restrict__ out_img) {
  int p = blockIdx.x * 256 + threadIdx.x;
  if (p >= NPIX) return;
  unsigned long long k = keys[p];
  float c0 = 0.f, c1 = 0.f, c2 = 0.f;
  if (k != SENTINEL) {
    int f = (int)(unsigned int)(k & 0xFFFFFFFFULL);
    float bz = __uint_as_float((unsigned int)(k >> 32));
    int xx = p & (SS - 1), yy = p >> 8;
    float px = (float)(2 * xx + 1 - SS) * (1.0f / 256.0f);
    float py = (float)(2 * yy + 1 - SS) * (1.0f / 256.0f);
    int ia = faces[f*3+0], ib = faces[f*3+1], ic = faces[f*3+2];
    float x0 = vb[ia*3+0], y0 = -vb[ia*3+1], z0 = vb[ia*3+2];
    float x1 = vb[ib*3+0], y1 = -vb[ib*3+1], z1 = vb[ib*3+2];
    float x2 = vb[ic*3+0], y2 = -vb[ic*3+1], z2 = vb[ic*3+2];
    float det = edgef(x1, y1, x2, y2, x0, y0);
    float e0 = edgef(x1, y1, x2, y2, px, py);
    float e1 = edgef(x2, y2, x0, y0, px, py);
    float e2 = edgef(x0, y0, x1, y1, px, py);
    float b0 = __fdiv_rn(e0, det);
    float b1 = __fdiv_rn(e1, det);
    float b2 = __fdiv_rn(e2, det);
    float rz0 = (fabsf(z0) > 1e-8f) ? z0 : 1.0f;
    float rz1 = (fabsf(z1) > 1e-8f) ? z1 : 1.0f;
    float rz2 = (fabsf(z2) > 1e-8f) ? z2 : 1.0f;
    float w0 = __fmul_rn(__fdiv_rn(b0, rz0), bz);
    float w1 = __fmul_rn(__fdiv_rn(b1, rz1), bz);
    float w2 = __fmul_rn(__fdiv_rn(b2, rz2), bz);
    float pos0 = fminf(fmaxf(w0, 0.f), 1.f) * 2.f;
    float pos1 = fminf(fmaxf(w1, 0.f), 1.f) * 2.f;
    float pos2 = fminf(fmaxf(w2, 0.f), 1.f) * 2.f;
    float i0f = fminf(fmaxf(floorf(pos0), 0.f), 1.f);
    float i1f = fminf(fmaxf(floorf(pos1), 0.f), 1.f);
    float i2f = fminf(fmaxf(floorf(pos2), 0.f), 1.f);
    float fr0 = fminf(fmaxf(__fsub_rn(pos0, i0f), 0.f), 1.f);
    float fr1 = fminf(fmaxf(__fsub_rn(pos1, i1f), 0.f), 1.f);
    float fr2 = fminf(fmaxf(__fsub_rn(pos2, i2f), 0.f), 1.f);
    int i00 = (int)i0f, i01 = (int)i1f;
    #pragma unroll
    for (int d0 = 0; d0 < 2; ++d0) {
      float wa = d0 ? fr0 : __fsub_rn(1.f, fr0);
      #pragma unroll
      for (int d1 = 0; d1 < 2; ++d1) {
        float wb = d1 ? fr1 : __fsub_rn(1.f, fr1);
        int a = min(i00 + d0, 2);
        int b = min(i01 + d1, 2);
        const float* tp = &out_tex[f * 81 + a * 27 + b * 9];  // k=0 slice
        float wab = __fmul_rn(wa, wb);
        #pragma unroll
        for (int d2 = 0; d2 < 2; ++d2) {
          float wc = d2 ? fr2 : __fsub_rn(1.f, fr2);
          float wgt = __fmul_rn(wab, wc);
          c0 = __fadd_rn(c0, __fmul_rn(wgt, tp[0]));
          c1 = __fadd_rn(c1, __fmul_rn(wgt, tp[1]));
          c2 = __fadd_rn(c2, __fmul_rn(wgt, tp[2]));
        }
      }
    }
  }
  out_img[p]           = c0;
  out_img[NPIX + p]    = c1;
  out_img[2*NPIX + p]  = c2;
}

extern "C" void kernel_launch(void* const* d_in, const int* in_sizes, int n_in,
                              void* d_out, int out_size, void* d_ws, size_t ws_size,
                              hipStream_t stream) {
  const float* cam   = (const float*)d_in[0];
  const float* verts = (const float*)d_in[1];
  const float* uv    = (const float*)d_in[2];
  const int*   faces = (const int*)d_in[3];
  float* out_img = (float*)d_out;            // (1,3,256,256)
  float* out_tex = (float*)d_out + 3 * NPIX; // (1,NF,3,3,3,3)

  char* ws = (char*)d_ws;
  unsigned long long* keys = (unsigned long long*)(ws + OFF_KEYS);
  float* vb                = (float*)(ws + OFF_VB);
  float* fd                = (float*)(ws + OFF_FD);
  unsigned int* pfx        = (unsigned int*)(ws + OFF_PFX);

  vert_k<<<(NVERT + 255) / 256, 256, 0, stream>>>(cam, verts, vb);
  init_k<<<NPIX / 256, 256, 0, stream>>>(keys);
  tex_k<<<(NFACE * 9 + 255) / 256, 256, 0, stream>>>(vb, faces, uv, out_tex);
  setup_k<<<(NFACE + 255) / 256, 256, 0, stream>>>(vb, faces, fd, pfx);
  scan_k<<<1, 1024, 0, stream>>>(pfx);
  rast2_k<<<NBLK_RAST, 256, 0, stream>>>(fd, pfx, keys);
  resolve_k<<<NPIX / 256, 256, 0, stream>>>(vb, faces, keys, out_tex, out_img);
}